// Round 7
// baseline (19302.968 us; speedup 1.0000x reference)
//
#include <hip/hip_runtime.h>
#include <stdint.h>

typedef unsigned int u32;
typedef unsigned short u16;

#define NB   2048
#define SS   256
#define HH   64
#define VV   4
#define LATD 3
#define NTHR 512   // 8 waves, wave = 1 batch row, 256 blocks = 1 block/CU, 2 waves/SIMD

// float-element offsets in d_out: recons [B,S,1,V], tokens [B,S], mu, log_var
#define TOK_OFF (NB*SS*VV)
#define MU_OFF  (TOK_OFF + NB*SS)
#define LV_OFF  (MU_OFF + NB*LATD)

// ---------- JAX threefry2x32 (20 rounds, explicit) ----------
__device__ __forceinline__ void tf2x32(u32 k0, u32 k1, u32 x0, u32 x1, u32& o0, u32& o1){
  u32 k2 = k0 ^ k1 ^ 0x1BD11BDAu;
  x0 += k0; x1 += k1;
#define TFR(r) { x0 += x1; x1 = (x1<<r)|(x1>>(32-r)); x1 ^= x0; }
  TFR(13) TFR(15) TFR(26) TFR(6)   x0 += k1; x1 += k2 + 1u;
  TFR(17) TFR(29) TFR(16) TFR(24)  x0 += k2; x1 += k0 + 2u;
  TFR(13) TFR(15) TFR(26) TFR(6)   x0 += k0; x1 += k1 + 3u;
  TFR(17) TFR(29) TFR(16) TFR(24)  x0 += k1; x1 += k2 + 4u;
  TFR(13) TFR(15) TFR(26) TFR(6)   x0 += k2; x1 += k0 + 5u;
#undef TFR
  o0 = x0; o1 = x1;
}
// partitionable random_bits (32-bit): bits[i] = x0 ^ x1 of counter (0, i)
__device__ __forceinline__ u32 foldb(u32 k0, u32 k1, u32 i){
  u32 a,b; tf2x32(k0,k1,0u,i,a,b); return a^b;
}
__device__ __forceinline__ float b2u(u32 bits){
  union{u32 i;float f;}c; c.i = (bits>>9) | 0x3f800000u; return c.f - 1.0f;
}
// XLA ErfInv32 (Giles)
__device__ __forceinline__ float erfinv_f(float x){
  float w = -log1pf(-x*x);
  float p;
  if (w < 5.0f){
    w -= 2.5f;
    p = 2.81022636e-08f;
    p = fmaf(p,w, 3.43273939e-07f);
    p = fmaf(p,w,-3.5233877e-06f);
    p = fmaf(p,w,-4.39150654e-06f);
    p = fmaf(p,w, 0.00021858087f);
    p = fmaf(p,w,-0.00125372503f);
    p = fmaf(p,w,-0.00417768164f);
    p = fmaf(p,w, 0.246640727f);
    p = fmaf(p,w, 1.50140941f);
  } else {
    w = sqrtf(w) - 3.0f;
    p = -0.000200214257f;
    p = fmaf(p,w, 0.000100950558f);
    p = fmaf(p,w, 0.00134934322f);
    p = fmaf(p,w,-0.00367342844f);
    p = fmaf(p,w, 0.00573950773f);
    p = fmaf(p,w,-0.0076224613f);
    p = fmaf(p,w, 0.00943887047f);
    p = fmaf(p,w, 1.00167406f);
    p = fmaf(p,w, 2.83297682f);
  }
  return p*x;
}
__device__ __forceinline__ float sigm(float x){ return 1.0f/(1.0f+expf(-x)); }
__device__ __forceinline__ float rl(float x, int l){
  return __int_as_float(__builtin_amdgcn_readlane(__float_as_int(x), l));
}
__device__ __forceinline__ float wred(float x){
  #pragma unroll
  for (int m=1; m<64; m<<=1) x += __shfl_xor(x, m, 64);
  return x;
}

// Single-row GRU mat-vec, REGISTER/L1-stream weights (lane j = output row j).
#define MATVEC1R(Wr, Wz, Wn, xv, ar, az, an)                                   \
  _Pragma("unroll")                                                            \
  for (int k4 = 0; k4 < 16; k4++){                                             \
    float4 wr = Wr[k4];                                                        \
    float4 wz = Wz[k4];                                                        \
    float4 wn = Wn[k4];                                                        \
    float x0 = rl(xv, 4*k4), x1 = rl(xv, 4*k4+1), x2 = rl(xv, 4*k4+2), x3 = rl(xv, 4*k4+3); \
    ar = fmaf(wr.x,x0,ar); ar = fmaf(wr.y,x1,ar); ar = fmaf(wr.z,x2,ar); ar = fmaf(wr.w,x3,ar); \
    az = fmaf(wz.x,x0,az); az = fmaf(wz.y,x1,az); az = fmaf(wz.z,x2,az); az = fmaf(wz.w,x3,az); \
    an = fmaf(wn.x,x0,an); an = fmaf(wn.y,x1,an); an = fmaf(wn.z,x2,an); an = fmaf(wn.w,x3,an); \
  }

// Single-row GRU mat-vec, LDS weights (layout w[k4*192 + gate*64 + j]).
#define MATVEC1L(W, xv, ar, az, an)                                            \
  _Pragma("unroll 2")                                                          \
  for (int k4 = 0; k4 < 16; k4++){                                             \
    float4 wr = W[k4*192 + j];                                                 \
    float4 wz = W[k4*192 + 64 + j];                                            \
    float4 wn = W[k4*192 + 128 + j];                                           \
    float x0 = rl(xv, 4*k4), x1 = rl(xv, 4*k4+1), x2 = rl(xv, 4*k4+2), x3 = rl(xv, 4*k4+3); \
    ar = fmaf(wr.x,x0,ar); ar = fmaf(wr.y,x1,ar); ar = fmaf(wr.z,x2,ar); ar = fmaf(wr.w,x3,ar); \
    az = fmaf(wz.x,x0,az); az = fmaf(wz.y,x1,az); az = fmaf(wz.z,x2,az); az = fmaf(wz.w,x3,az); \
    an = fmaf(wn.x,x0,an); an = fmaf(wn.y,x1,an); an = fmaf(wn.z,x2,an); an = fmaf(wn.w,x3,an); \
  }

// Single-row GRU mat-vec, GLOBAL weights streamed through L1/L2 (same proven
// pattern as the Whh0 stream). Addresses are loop-invariant; the per-iteration
// reload is enforced by the loop-top memory fence (anti-spill). Iteration and
// summation order identical to MATVEC1L -> bit-identical results; moves 48
// ds_read_b128/step/wave from the LDS pipe to the idle VMEM pipe.
#define MATVEC1G(Gp, xv, ar, az, an)                                           \
  _Pragma("unroll")                                                            \
  for (int k4 = 0; k4 < 16; k4++){                                             \
    float4 wr = Gp[(j)*16 + k4];                                               \
    float4 wz = Gp[(64 + j)*16 + k4];                                          \
    float4 wn = Gp[(128 + j)*16 + k4];                                         \
    float x0 = rl(xv, 4*k4), x1 = rl(xv, 4*k4+1), x2 = rl(xv, 4*k4+2), x3 = rl(xv, 4*k4+3); \
    ar = fmaf(wr.x,x0,ar); ar = fmaf(wr.y,x1,ar); ar = fmaf(wr.z,x2,ar); ar = fmaf(wr.w,x3,ar); \
    az = fmaf(wz.x,x0,az); az = fmaf(wz.y,x1,az); az = fmaf(wz.z,x2,az); az = fmaf(wz.w,x3,az); \
    an = fmaf(wn.x,x0,an); an = fmaf(wn.y,x1,an); an = fmaf(wn.z,x2,an); an = fmaf(wn.w,x3,an); \
  }

#define LOAD_REG_W(G, Ar, Az, An)                                              \
  _Pragma("unroll")                                                            \
  for (int k4 = 0; k4 < 16; k4++){                                             \
    Ar[k4] = G[(j)*16 + k4];                                                   \
    Az[k4] = G[(64 + j)*16 + k4];                                              \
    An[k4] = G[(128 + j)*16 + k4];                                             \
  }

// PIN (enc only): measured best enc config (R9, ~1068 us). Neutral in dec.
#define PIN4(v) asm volatile("" : "+v"(v.x), "+v"(v.y), "+v"(v.z), "+v"(v.w))
#define PIN_W(Ar, Az, An)                                                      \
  _Pragma("unroll")                                                            \
  for (int k4 = 0; k4 < 16; k4++){ PIN4(Ar[k4]); PIN4(Az[k4]); PIN4(An[k4]); }

// =====================================================================
// Encoder: R9 structure with wh1 moved LDS -> global stream.
// LDS b128/step/wave: 96 -> 48 (floor 9216 -> 4608 cyc/CU/step); the
// wh1 stream rides the proven Whh0 VMEM path (weights L2-resident).
// =====================================================================
__global__ __launch_bounds__(NTHR, 2) void enc_kernel(
    const int* __restrict__ tokens, const float* __restrict__ emb,
    const float* __restrict__ Wih0, const float* __restrict__ Whh0,
    const float* __restrict__ bih0, const float* __restrict__ bhh0,
    const float* __restrict__ Wih1, const float* __restrict__ Whh1,
    const float* __restrict__ bih1, const float* __restrict__ bhh1,
    const float* __restrict__ muW, const float* __restrict__ mub,
    const float* __restrict__ vaW, const float* __restrict__ vab,
    const float* __restrict__ pW,  const float* __restrict__ pb,
    float* __restrict__ out, float* __restrict__ hz_ws)
{
  __shared__ float4 wi1[16*192];  // enc_Wih1 (critical-chain matvec stays LDS)
  __shared__ float tokT[VV*192];  // input-gate table (incl. bih0) per vocab token

  const int tid = threadIdx.x;
  const int b0  = blockIdx.x * 8;
  const int j   = tid & 63;
  const int wv  = tid >> 6;
  const int row = b0 + wv;

  for (int i4 = tid; i4 < 3072; i4 += NTHR){
    int g = i4 >> 4, k4 = i4 & 15;
    wi1[k4*192 + g] = ((const float4*)Wih1)[i4];
  }
  if (tid < 192){
    #pragma unroll
    for (int v = 0; v < VV; v++){
      float acc = 0.0f;
      #pragma unroll
      for (int e = 0; e < 8; e++) acc = fmaf(emb[v*8+e], Wih0[tid*8+e], acc);
      tokT[v*192 + tid] = acc + bih0[tid];
    }
  }
  for (int i = tid; i < 8*SS; i += NTHR){
    int rr = i >> 8, tq = i & 255;
    out[TOK_OFF + (b0+rr)*SS + tq] = (float)tokens[(b0+rr)*SS + tq];
  }

  float4 w0r[16], w0z[16], w0n[16];
  {
    const float4* G0 = (const float4*)Whh0;
    LOAD_REG_W(G0, w0r, w0z, w0n)
    PIN_W(w0r, w0z, w0n)
  }
  __syncthreads();

  const float4* Gh1 = (const float4*)Whh1;

  const float bhr0 = bhh0[j], bhz0 = bhh0[64+j], bhn0 = bhh0[128+j];
  const float bir1 = bih1[j], biz1 = bih1[64+j], bin1 = bih1[128+j];
  const float bhr1 = bhh1[j], bhz1 = bhh1[64+j], bhn1 = bhh1[128+j];

  float h0 = 0.0f, h1 = 0.0f;
  const int tR = row*SS;

  for (int t = 0; t < SS; t++){
    // LICM fence (round-3: hoist -> spill -> 13.3 GB HBM refill traffic)
    asm volatile("" ::: "memory");
    int k = tokens[tR + t];
    // wh1 partials first: global loads (loop-invariant addresses) issue at
    // step start, latency hidden under matvec0 + combine0 + wi1 compute.
    float ahr=0, ahz=0, ahn=0;
    MATVEC1G(Gh1, h1, ahr, ahz, ahn)
    float ar=0, az=0, an=0;
    MATVEC1R(w0r, w0z, w0n, h0, ar, az, an)
    {
      float ir = tokT[k*192+j], iz = tokT[k*192+64+j], ig = tokT[k*192+128+j];
      float rg = sigm(ir + ar + bhr0);
      float zg = sigm(iz + az + bhz0);
      float ng = tanhf(ig + rg*(an + bhn0));
      h0 = (1.0f - zg)*ng + zg*h0;
    }
    float air=0, aiz=0, ain=0;
    MATVEC1L(wi1, h0, air, aiz, ain)
    {
      float rg = sigm(air + bir1 + ahr + bhr1);
      float zg = sigm(aiz + biz1 + ahz + bhz1);
      float ng = tanhf(ain + bin1 + rg*(ahn + bhn1));
      h1 = (1.0f - zg)*ng + zg*h1;
    }
  }

  const float LO_ = -0.99999994f;   // nextafter(-1, 0) in f32
  {
    float hv = h1;
    int gb = row;
    float mu0,mu1,mu2, lv0,lv1,lv2;
    { float pm = muW[0*64+j]*hv; pm = wred(pm); mu0 = pm + mub[0];
      float pv = vaW[0*64+j]*hv; pv = wred(pv); lv0 = pv + vab[0]; }
    { float pm = muW[1*64+j]*hv; pm = wred(pm); mu1 = pm + mub[1];
      float pv = vaW[1*64+j]*hv; pv = wred(pv); lv1 = pv + vab[1]; }
    { float pm = muW[2*64+j]*hv; pm = wred(pm); mu2 = pm + mub[2];
      float pv = vaW[2*64+j]*hv; pv = wred(pv); lv2 = pv + vab[2]; }
    if (j < 3){
      float mv  = (j==0)?mu0:(j==1)?mu1:mu2;
      float lvv = (j==0)?lv0:(j==1)?lv1:lv2;
      out[MU_OFF + gb*LATD + j] = mv;
      out[LV_OFF + gb*LATD + j] = lvv;
    }
    float z0,z1,z2;
    #pragma unroll
    for (int l = 0; l < 3; l++){
      u32 bits = foldb(0u, 1u, (u32)(gb*LATD + l));
      float u01 = b2u(bits);
      float uu = u01 * 2.0f;      // (hi - lo) rounds to 2.0f
      uu = uu + LO_;
      uu = fmaxf(LO_, uu);
      float ep = 1.41421354f * erfinv_f(uu);
      float lvv = (l==0)?lv0:(l==1)?lv1:lv2;
      float mvv = (l==0)?mu0:(l==1)?mu1:mu2;
      float zv = ep * expf(0.5f*lvv) + mvv;
      if (l==0) z0 = zv; else if (l==1) z1 = zv; else z2 = zv;
    }
    float hzj = pW[j*3+0]*z0;
    hzj += pW[j*3+1]*z1;
    hzj += pW[j*3+2]*z2;
    hzj += pb[j];
    hz_ws[gb*HH + j] = hzj;
  }
}

// =====================================================================
// Decoder: R4 body (stagger reverted, pin reverted) with wh1 moved
// LDS -> global stream. wh1 is the carried (latency-tolerant) matvec;
// wi1 (critical chain) stays in LDS.
// =====================================================================
__global__ __launch_bounds__(NTHR, 2) void dec_kernel(
    const float* __restrict__ demb,
    const float* __restrict__ Wih0, const float* __restrict__ Whh0,
    const float* __restrict__ bih0, const float* __restrict__ bhh0,
    const float* __restrict__ Wih1, const float* __restrict__ Whh1,
    const float* __restrict__ bih1, const float* __restrict__ bhh1,
    const float* __restrict__ headW, const float* __restrict__ headb,
    const float* __restrict__ hz_ws, float* __restrict__ out)
{
  __shared__ float4 wi1[16*192];  // dec_Wih1 (critical-chain matvec stays LDS)
  __shared__ float decT[6*192];   // input-gate table (incl. bih0) per token
  __shared__ u32 sk0[SS], sk1[SS];
  __shared__ float gmbT[8][SS*VV]; // precomputed gumbel per (local row, t, vv)

  const int tid = threadIdx.x;
  const int b0  = blockIdx.x * 8;
  const int j   = tid & 63;
  const int wv  = tid >> 6;
  const int row = b0 + wv;

  for (int i4 = tid; i4 < 3072; i4 += NTHR){
    int g = i4 >> 4, k4 = i4 & 15;
    wi1[k4*192 + g] = ((const float4*)Wih1)[i4];
  }
  if (tid < 192){
    #pragma unroll
    for (int v = 0; v < 6; v++){
      float acc = 0.0f;
      #pragma unroll 8
      for (int k = 0; k < 64; k++) acc = fmaf(demb[v*64+k], Wih0[tid*64+k], acc);
      decT[v*192 + tid] = acc + bih0[tid];
    }
  }
  // split(key(2), 256): key_t = full output pair of threefry(key2, (0, t))
  if (tid < SS){
    u32 a,b; tf2x32(0u, 2u, 0u, (u32)tid, a, b);
    sk0[tid] = a; sk1[tid] = b;
  }

  float4 w0r[16], w0z[16], w0n[16];
  {
    const float4* G0 = (const float4*)Whh0;
    LOAD_REG_W(G0, w0r, w0z, w0n)   // no PIN: L1 streaming (R7 measured best)
  }
  __syncthreads();

  const float TINY = 1.17549435e-38f;
  // Precompute gumbel table for this wave's row: IDENTICAL formula/inputs as
  // the old in-loop computation -> bit-identical values. Written and read by
  // the same wave only (no extra barrier needed).
  for (int idx = j; idx < SS*VV; idx += 64){
    int t = idx >> 2, v = idx & 3;
    u32 bits = foldb(sk0[t], sk1[t], (u32)(row*VV + v));
    float u01 = b2u(bits);
    float u = u01 + TINY;          // scale (1 - tiny) rounds to 1.0f
    u = fmaxf(TINY, u);
    gmbT[wv][idx] = -logf(-logf(u));
  }

  const float4* Gh1 = (const float4*)Whh1;

  const float bhr0 = bhh0[j], bhz0 = bhh0[64+j], bhn0 = bhh0[128+j];
  const float bir1 = bih1[j], biz1 = bih1[64+j], bin1 = bih1[128+j];
  const float bhr1 = bhh1[j], bhz1 = bhh1[64+j], bhn1 = bhh1[128+j];
  const float hw0 = headW[0*64+j], hw1 = headW[1*64+j], hw2 = headW[2*64+j], hw3 = headW[3*64+j];
  const float hb0 = headb[0], hb1 = headb[1], hb2 = headb[2], hb3 = headb[3];

  float h0 = hz_ws[row*HH + j];
  float h1 = h0;
  int tk = 4;                     // START token

  const int vv = j & 3;           // lane's vocab slot (quads replicate)

  // pipeline prologue: layer-0 partials AND layer-1 hh partials for t=0
  float ar=0, az=0, an=0;
  MATVEC1R(w0r, w0z, w0n, h0, ar, az, an)
  float ahr=0, ahz=0, ahn=0;
  MATVEC1G(Gh1, h1, ahr, ahz, ahn)

  for (int t = 0; t < SS; t++){
    asm volatile("" ::: "memory");   // LICM fence (see enc_kernel comment)
    // ---- layer 0 gate combine (partials carried; token from prev sample) ----
    {
      float ir = decT[tk*192+j], iz = decT[tk*192+64+j], ig = decT[tk*192+128+j];
      float rg = sigm(ir + ar + bhr0);
      float zg = sigm(iz + az + bhz0);
      float ng = tanhf(ig + rg*(an + bhn0));
      h0 = (1.0f - zg)*ng + zg*h0;
    }
    // ---- layer 1: ih-matvec (critical chain, LDS) + combine with carried hh ----
    float air=0, aiz=0, ain=0;
    MATVEC1L(wi1, h0, air, aiz, ain)
    {
      float rg = sigm(air + bir1 + ahr + bhr1);
      float zg = sigm(aiz + biz1 + ahz + bhz1);
      float ng = tanhf(ain + bin1 + rg*(ahn + bhn1));
      h1 = (1.0f - zg)*ng + zg*h1;
    }
    // ---- independent fill work for step t+1 (overlaps head/sample chain):
    //      gumbel read, layer-0 matvec on h0(t), layer-1 hh-matvec on h1(t)
    //      (wh1 now a VMEM stream: loads issue here, resolve under sample) ----
    float gmb = gmbT[wv][t*VV + vv];
    ar = 0.0f; az = 0.0f; an = 0.0f;
    MATVEC1R(w0r, w0z, w0n, h0, ar, az, an)
    ahr = 0.0f; ahz = 0.0f; ahn = 0.0f;
    MATVEC1G(Gh1, h1, ahr, ahz, ahn)
    // ---- head logits (wave reductions) ----
    float l0 = wred(hw0*h1) + hb0;
    float l1 = wred(hw1*h1) + hb1;
    float l2 = wred(hw2*h1) + hb2;
    float l3 = wred(hw3*h1) + hb3;
    // ---- gumbel sample + softmax (quad-parallel, all lanes uniform) ----
    float lg = (vv==0)?l0:(vv==1)?l1:(vv==2)?l2:l3;
    float prt = lg + gmb;
    // softmax over quad
    float mx = lg;
    mx = fmaxf(mx, __shfl_xor(mx, 1, 64));
    mx = fmaxf(mx, __shfl_xor(mx, 2, 64));
    float e = expf(lg - mx);
    float se = e;
    se += __shfl_xor(se, 1, 64);
    se += __shfl_xor(se, 2, 64);
    float prob = e / se;
    // argmax over quad (first-index tie-break)
    float bp = prt; int bv = vv;
    { float o = __shfl_xor(bp, 1, 64); int ov = __shfl_xor(bv, 1, 64);
      if (o > bp || (o == bp && ov < bv)){ bp = o; bv = ov; } }
    { float o = __shfl_xor(bp, 2, 64); int ov = __shfl_xor(bv, 2, 64);
      if (o > bp || (o == bp && ov < bv)){ bp = o; bv = ov; } }
    if (j < 4) out[(size_t)row*SS*VV + (size_t)t*VV + vv] = prob;
    tk = __builtin_amdgcn_readlane(bv, 0);
  }
}

extern "C" void kernel_launch(void* const* d_in, const int* in_sizes, int n_in,
                              void* d_out, int out_size, void* d_ws, size_t ws_size,
                              hipStream_t stream){
  const int*   tokens = (const int*)d_in[0];
  const float* emb    = (const float*)d_in[1];
  const float* eWih0  = (const float*)d_in[2];  const float* eWhh0 = (const float*)d_in[3];
  const float* ebih0  = (const float*)d_in[4];  const float* ebhh0 = (const float*)d_in[5];
  const float* eWih1  = (const float*)d_in[6];  const float* eWhh1 = (const float*)d_in[7];
  const float* ebih1  = (const float*)d_in[8];  const float* ebhh1 = (const float*)d_in[9];
  const float* muW    = (const float*)d_in[10]; const float* mub   = (const float*)d_in[11];
  const float* vaW    = (const float*)d_in[12]; const float* vab   = (const float*)d_in[13];
  const float* demb   = (const float*)d_in[14];
  const float* pW     = (const float*)d_in[15]; const float* pb    = (const float*)d_in[16];
  const float* dWih0  = (const float*)d_in[17]; const float* dWhh0 = (const float*)d_in[18];
  const float* dbih0  = (const float*)d_in[19]; const float* dbhh0 = (const float*)d_in[20];
  const float* dWih1  = (const float*)d_in[21]; const float* dWhh1 = (const float*)d_in[22];
  const float* dbih1  = (const float*)d_in[23]; const float* dbhh1 = (const float*)d_in[24];
  const float* hWp    = (const float*)d_in[25]; const float* hbp   = (const float*)d_in[26];
  float* out = (float*)d_out;
  float* hz = (float*)d_ws;   // B*H fp32 = 512 KB scratch

  enc_kernel<<<NB/8, NTHR, 0, stream>>>(tokens, emb,
      eWih0, eWhh0, ebih0, ebhh0, eWih1, eWhh1, ebih1, ebhh1,
      muW, mub, vaW, vab, pW, pb, out, hz);
  dec_kernel<<<NB/8, NTHR, 0, stream>>>(demb,
      dWih0, dWhh0, dbih0, dbhh0, dWih1, dWhh1, dbih1, dbhh1,
      hWp, hbp, hz, out);
}

// Round 8
// 2576.654 us; speedup vs baseline: 7.4915x; 7.4915x over previous
//
#include <hip/hip_runtime.h>
#include <stdint.h>

typedef unsigned int u32;

#define NB   2048
#define SS   256
#define HH   64
#define VV   4
#define LATD 3
#define NTHR 512   // 8 waves, wave = 1 batch row (enc AND dec phase), 256 blocks

// float-element offsets in d_out: recons [B,S,1,V], tokens [B,S], mu, log_var
#define TOK_OFF (NB*SS*VV)
#define MU_OFF  (TOK_OFF + NB*SS)
#define LV_OFF  (MU_OFF + NB*LATD)

// ---------- JAX threefry2x32 (20 rounds, explicit) ----------
__device__ __forceinline__ void tf2x32(u32 k0, u32 k1, u32 x0, u32 x1, u32& o0, u32& o1){
  u32 k2 = k0 ^ k1 ^ 0x1BD11BDAu;
  x0 += k0; x1 += k1;
#define TFR(r) { x0 += x1; x1 = (x1<<r)|(x1>>(32-r)); x1 ^= x0; }
  TFR(13) TFR(15) TFR(26) TFR(6)   x0 += k1; x1 += k2 + 1u;
  TFR(17) TFR(29) TFR(16) TFR(24)  x0 += k2; x1 += k0 + 2u;
  TFR(13) TFR(15) TFR(26) TFR(6)   x0 += k0; x1 += k1 + 3u;
  TFR(17) TFR(29) TFR(16) TFR(24)  x0 += k1; x1 += k2 + 4u;
  TFR(13) TFR(15) TFR(26) TFR(6)   x0 += k2; x1 += k0 + 5u;
#undef TFR
  o0 = x0; o1 = x1;
}
// partitionable random_bits (32-bit): bits[i] = x0 ^ x1 of counter (0, i)
__device__ __forceinline__ u32 foldb(u32 k0, u32 k1, u32 i){
  u32 a,b; tf2x32(k0,k1,0u,i,a,b); return a^b;
}
__device__ __forceinline__ float b2u(u32 bits){
  union{u32 i;float f;}c; c.i = (bits>>9) | 0x3f800000u; return c.f - 1.0f;
}
// XLA ErfInv32 (Giles)
__device__ __forceinline__ float erfinv_f(float x){
  float w = -log1pf(-x*x);
  float p;
  if (w < 5.0f){
    w -= 2.5f;
    p = 2.81022636e-08f;
    p = fmaf(p,w, 3.43273939e-07f);
    p = fmaf(p,w,-3.5233877e-06f);
    p = fmaf(p,w,-4.39150654e-06f);
    p = fmaf(p,w, 0.00021858087f);
    p = fmaf(p,w,-0.00125372503f);
    p = fmaf(p,w,-0.00417768164f);
    p = fmaf(p,w, 0.246640727f);
    p = fmaf(p,w, 1.50140941f);
  } else {
    w = sqrtf(w) - 3.0f;
    p = -0.000200214257f;
    p = fmaf(p,w, 0.000100950558f);
    p = fmaf(p,w, 0.00134934322f);
    p = fmaf(p,w,-0.00367342844f);
    p = fmaf(p,w, 0.00573950773f);
    p = fmaf(p,w,-0.0076224613f);
    p = fmaf(p,w, 0.00943887047f);
    p = fmaf(p,w, 1.00167406f);
    p = fmaf(p,w, 2.83297682f);
  }
  return p*x;
}
__device__ __forceinline__ float sigm(float x){ return 1.0f/(1.0f+expf(-x)); }
__device__ __forceinline__ float rl(float x, int l){
  return __int_as_float(__builtin_amdgcn_readlane(__float_as_int(x), l));
}
__device__ __forceinline__ float wred(float x){
  #pragma unroll
  for (int m=1; m<64; m<<=1) x += __shfl_xor(x, m, 64);
  return x;
}

// Single-row GRU mat-vec, REGISTER/L1-stream weights (lane j = output row j).
#define MATVEC1R(Wr, Wz, Wn, xv, ar, az, an)                                   \
  _Pragma("unroll")                                                            \
  for (int k4 = 0; k4 < 16; k4++){                                             \
    float4 wr = Wr[k4];                                                        \
    float4 wz = Wz[k4];                                                        \
    float4 wn = Wn[k4];                                                        \
    float x0 = rl(xv, 4*k4), x1 = rl(xv, 4*k4+1), x2 = rl(xv, 4*k4+2), x3 = rl(xv, 4*k4+3); \
    ar = fmaf(wr.x,x0,ar); ar = fmaf(wr.y,x1,ar); ar = fmaf(wr.z,x2,ar); ar = fmaf(wr.w,x3,ar); \
    az = fmaf(wz.x,x0,az); az = fmaf(wz.y,x1,az); az = fmaf(wz.z,x2,az); az = fmaf(wz.w,x3,az); \
    an = fmaf(wn.x,x0,an); an = fmaf(wn.y,x1,an); an = fmaf(wn.z,x2,an); an = fmaf(wn.w,x3,an); \
  }

// Single-row GRU mat-vec, LDS weights (layout w[k4*192 + gate*64 + j]).
#define MATVEC1L(W, xv, ar, az, an)                                            \
  _Pragma("unroll 2")                                                          \
  for (int k4 = 0; k4 < 16; k4++){                                             \
    float4 wr = W[k4*192 + j];                                                 \
    float4 wz = W[k4*192 + 64 + j];                                            \
    float4 wn = W[k4*192 + 128 + j];                                           \
    float x0 = rl(xv, 4*k4), x1 = rl(xv, 4*k4+1), x2 = rl(xv, 4*k4+2), x3 = rl(xv, 4*k4+3); \
    ar = fmaf(wr.x,x0,ar); ar = fmaf(wr.y,x1,ar); ar = fmaf(wr.z,x2,ar); ar = fmaf(wr.w,x3,ar); \
    az = fmaf(wz.x,x0,az); az = fmaf(wz.y,x1,az); az = fmaf(wz.z,x2,az); az = fmaf(wz.w,x3,az); \
    an = fmaf(wn.x,x0,an); an = fmaf(wn.y,x1,an); an = fmaf(wn.z,x2,an); an = fmaf(wn.w,x3,an); \
  }

#define LOAD_REG_W(G, Ar, Az, An)                                              \
  _Pragma("unroll")                                                            \
  for (int k4 = 0; k4 < 16; k4++){                                             \
    Ar[k4] = G[(j)*16 + k4];                                                   \
    Az[k4] = G[(64 + j)*16 + k4];                                              \
    An[k4] = G[(128 + j)*16 + k4];                                             \
  }

// PIN (enc only): measured best enc config (~1068 us). Neutral in dec.
#define PIN4(v) asm volatile("" : "+v"(v.x), "+v"(v.y), "+v"(v.z), "+v"(v.w))
#define PIN_W(Ar, Az, An)                                                      \
  _Pragma("unroll")                                                            \
  for (int k4 = 0; k4 < 16; k4++){ PIN4(Ar[k4]); PIN4(Az[k4]); PIN4(An[k4]); }

// =====================================================================
// Fused VAE kernel: enc phase (R9/R3 config, measured ~1050us) then dec
// phase (R4 config, measured ~1490us) in ONE launch. Each wave's dec row
// equals its enc row, so hz passes in a register (no hz_ws round-trip);
// the LDS weight buffers are re-staged between phases behind a barrier.
// Weight-placement lessons (R1/R2/R5/R6/R7 all regressed): 8 independent
// waves, wi1+wh1 in LDS, Whh0 via the L1 stream, NO reg-pinning beyond
// the proven enc-w0 PIN, NO global weight streams, NO barriers in loops.
// Dec head: quad-first butterfly (12 cross-lane ops vs 24) — balanced-
// tree reorder only (same class as R1/R2 reorders, which passed).
// =====================================================================
__global__ __launch_bounds__(NTHR, 2) void vae_kernel(
    const int* __restrict__ tokens, const float* __restrict__ emb,
    const float* __restrict__ eWih0, const float* __restrict__ eWhh0,
    const float* __restrict__ ebih0, const float* __restrict__ ebhh0,
    const float* __restrict__ eWih1, const float* __restrict__ eWhh1,
    const float* __restrict__ ebih1, const float* __restrict__ ebhh1,
    const float* __restrict__ muW, const float* __restrict__ mub,
    const float* __restrict__ vaW, const float* __restrict__ vab,
    const float* __restrict__ demb,
    const float* __restrict__ pW,  const float* __restrict__ pb,
    const float* __restrict__ dWih0, const float* __restrict__ dWhh0,
    const float* __restrict__ dbih0, const float* __restrict__ dbhh0,
    const float* __restrict__ dWih1, const float* __restrict__ dWhh1,
    const float* __restrict__ dbih1, const float* __restrict__ dbhh1,
    const float* __restrict__ headW, const float* __restrict__ headb,
    float* __restrict__ out)
{
  __shared__ float4 wi1[16*192];   // phase-reused: enc_Wih1 then dec_Wih1
  __shared__ float4 wh1[16*192];   // phase-reused: enc_Whh1 then dec_Whh1
  __shared__ float tokT[VV*192];   // enc input-gate table per vocab token
  __shared__ float decT[6*192];    // dec input-gate table per token
  __shared__ float gmbT[8][SS*VV]; // precomputed gumbel per (local row, t, vv)

  const int tid = threadIdx.x;
  const int b0  = blockIdx.x * 8;
  const int j   = tid & 63;
  const int wv  = tid >> 6;
  const int row = b0 + wv;

  float4 w0r[16], w0z[16], w0n[16];
  float hzj;                       // enc->dec handoff (this wave's row)

  // ================= ENC PHASE =================
  {
    for (int i4 = tid; i4 < 3072; i4 += NTHR){
      int g = i4 >> 4, k4 = i4 & 15;
      wi1[k4*192 + g] = ((const float4*)eWih1)[i4];
      wh1[k4*192 + g] = ((const float4*)eWhh1)[i4];
    }
    if (tid < 192){
      #pragma unroll
      for (int v = 0; v < VV; v++){
        float acc = 0.0f;
        #pragma unroll
        for (int e = 0; e < 8; e++) acc = fmaf(emb[v*8+e], eWih0[tid*8+e], acc);
        tokT[v*192 + tid] = acc + ebih0[tid];
      }
    }
    for (int i = tid; i < 8*SS; i += NTHR){
      int rr = i >> 8, tq = i & 255;
      out[TOK_OFF + (b0+rr)*SS + tq] = (float)tokens[(b0+rr)*SS + tq];
    }

    {
      const float4* G0 = (const float4*)eWhh0;
      LOAD_REG_W(G0, w0r, w0z, w0n)
      PIN_W(w0r, w0z, w0n)
    }
    __syncthreads();

    const float bhr0 = ebhh0[j], bhz0 = ebhh0[64+j], bhn0 = ebhh0[128+j];
    const float bir1 = ebih1[j], biz1 = ebih1[64+j], bin1 = ebih1[128+j];
    const float bhr1 = ebhh1[j], bhz1 = ebhh1[64+j], bhn1 = ebhh1[128+j];

    float h0 = 0.0f, h1 = 0.0f;
    const int tR = row*SS;

    for (int t = 0; t < SS; t++){
      // LICM fence (hoist -> spill protection; see session journal R3/R6/R7)
      asm volatile("" ::: "memory");
      int k = tokens[tR + t];
      float ar=0, az=0, an=0;
      MATVEC1R(w0r, w0z, w0n, h0, ar, az, an)
      {
        float ir = tokT[k*192+j], iz = tokT[k*192+64+j], ig = tokT[k*192+128+j];
        float rg = sigm(ir + ar + bhr0);
        float zg = sigm(iz + az + bhz0);
        float ng = tanhf(ig + rg*(an + bhn0));
        h0 = (1.0f - zg)*ng + zg*h0;
      }
      float air=0, aiz=0, ain=0, ahr=0, ahz=0, ahn=0;
      MATVEC1L(wi1, h0, air, aiz, ain)
      MATVEC1L(wh1, h1, ahr, ahz, ahn)
      {
        float rg = sigm(air + bir1 + ahr + bhr1);
        float zg = sigm(aiz + biz1 + ahz + bhz1);
        float ng = tanhf(ain + bin1 + rg*(ahn + bhn1));
        h1 = (1.0f - zg)*ng + zg*h1;
      }
    }

    // ---- enc tail: mu/log_var/z/hz for this wave's row ----
    const float LO_ = -0.99999994f;   // nextafter(-1, 0) in f32
    float hv = h1;
    int gb = row;
    float mu0,mu1,mu2, lv0,lv1,lv2;
    { float pm = muW[0*64+j]*hv; pm = wred(pm); mu0 = pm + mub[0];
      float pv = vaW[0*64+j]*hv; pv = wred(pv); lv0 = pv + vab[0]; }
    { float pm = muW[1*64+j]*hv; pm = wred(pm); mu1 = pm + mub[1];
      float pv = vaW[1*64+j]*hv; pv = wred(pv); lv1 = pv + vab[1]; }
    { float pm = muW[2*64+j]*hv; pm = wred(pm); mu2 = pm + mub[2];
      float pv = vaW[2*64+j]*hv; pv = wred(pv); lv2 = pv + vab[2]; }
    if (j < 3){
      float mv  = (j==0)?mu0:(j==1)?mu1:mu2;
      float lvv = (j==0)?lv0:(j==1)?lv1:lv2;
      out[MU_OFF + gb*LATD + j] = mv;
      out[LV_OFF + gb*LATD + j] = lvv;
    }
    float z0,z1,z2;
    #pragma unroll
    for (int l = 0; l < 3; l++){
      u32 bits = foldb(0u, 1u, (u32)(gb*LATD + l));
      float u01 = b2u(bits);
      float uu = u01 * 2.0f;      // (hi - lo) rounds to 2.0f
      uu = uu + LO_;
      uu = fmaxf(LO_, uu);
      float ep = 1.41421354f * erfinv_f(uu);
      float lvv = (l==0)?lv0:(l==1)?lv1:lv2;
      float mvv = (l==0)?mu0:(l==1)?mu1:mu2;
      float zv = ep * expf(0.5f*lvv) + mvv;
      if (l==0) z0 = zv; else if (l==1) z1 = zv; else z2 = zv;
    }
    hzj = pW[j*3+0]*z0;
    hzj += pW[j*3+1]*z1;
    hzj += pW[j*3+2]*z2;
    hzj += pb[j];
  }

  // ================= DEC RESTAGE =================
  __syncthreads();   // all waves done reading enc wi1/wh1
  for (int i4 = tid; i4 < 3072; i4 += NTHR){
    int g = i4 >> 4, k4 = i4 & 15;
    wi1[k4*192 + g] = ((const float4*)dWih1)[i4];
    wh1[k4*192 + g] = ((const float4*)dWhh1)[i4];
  }
  if (tid < 192){
    #pragma unroll
    for (int v = 0; v < 6; v++){
      float acc = 0.0f;
      #pragma unroll 8
      for (int k = 0; k < 64; k++) acc = fmaf(demb[v*64+k], dWih0[tid*64+k], acc);
      decT[v*192 + tid] = acc + dbih0[tid];
    }
  }
  {
    const float TINY = 1.17549435e-38f;
    // Gumbel table for this wave's row. Keys inline: split(key(2),256) ->
    // key_t = full output pair of threefry(key2, (0, t)). Identical values
    // to the previous sk0/sk1+foldb path.
    for (int idx = j; idx < SS*VV; idx += 64){
      int t = idx >> 2, v = idx & 3;
      u32 a,b; tf2x32(0u, 2u, 0u, (u32)t, a, b);
      u32 bits = foldb(a, b, (u32)(row*VV + v));
      float u01 = b2u(bits);
      float u = u01 + TINY;        // scale (1 - tiny) rounds to 1.0f
      u = fmaxf(TINY, u);
      gmbT[wv][idx] = -logf(-logf(u));
    }
  }
  {
    const float4* G0 = (const float4*)dWhh0;
    LOAD_REG_W(G0, w0r, w0z, w0n)   // no PIN: L1 streaming (measured best in dec)
  }
  __syncthreads();

  // ================= DEC PHASE =================
  {
    const float bhr0 = dbhh0[j], bhz0 = dbhh0[64+j], bhn0 = dbhh0[128+j];
    const float bir1 = dbih1[j], biz1 = dbih1[64+j], bin1 = dbih1[128+j];
    const float bhr1 = dbhh1[j], bhz1 = dbhh1[64+j], bhn1 = dbhh1[128+j];
    const float hw0 = headW[0*64+j], hw1 = headW[1*64+j], hw2 = headW[2*64+j], hw3 = headW[3*64+j];
    const float hb0 = headb[0], hb1 = headb[1], hb2 = headb[2], hb3 = headb[3];

    float h0 = hzj;
    float h1 = h0;
    int tk = 4;                     // START token

    const int vv = j & 3;           // lane's vocab slot (quads replicate)
    const float hbv = (vv==0)?hb0:(vv==1)?hb1:(vv==2)?hb2:hb3;

    // pipeline prologue: layer-0 partials AND layer-1 hh partials for t=0
    float ar=0, az=0, an=0;
    MATVEC1R(w0r, w0z, w0n, h0, ar, az, an)
    float ahr=0, ahz=0, ahn=0;
    MATVEC1L(wh1, h1, ahr, ahz, ahn)

    for (int t = 0; t < SS; t++){
      asm volatile("" ::: "memory");   // LICM fence
      // ---- layer 0 gate combine (partials carried; token from prev sample) ----
      {
        float ir = decT[tk*192+j], iz = decT[tk*192+64+j], ig = decT[tk*192+128+j];
        float rg = sigm(ir + ar + bhr0);
        float zg = sigm(iz + az + bhz0);
        float ng = tanhf(ig + rg*(an + bhn0));
        h0 = (1.0f - zg)*ng + zg*h0;
      }
      // ---- layer 1: ih-matvec (critical chain) + combine with carried hh ----
      float air=0, aiz=0, ain=0;
      MATVEC1L(wi1, h0, air, aiz, ain)
      {
        float rg = sigm(air + bir1 + ahr + bhr1);
        float zg = sigm(aiz + biz1 + ahz + bhz1);
        float ng = tanhf(ain + bin1 + rg*(ahn + bhn1));
        h1 = (1.0f - zg)*ng + zg*h1;
      }
      // ---- independent fill work for step t+1 (overlaps head/sample chain) ----
      float gmb = gmbT[wv][t*VV + vv];
      ar = 0.0f; az = 0.0f; an = 0.0f;
      MATVEC1R(w0r, w0z, w0n, h0, ar, az, an)
      ahr = 0.0f; ahz = 0.0f; ahn = 0.0f;
      MATVEC1L(wh1, h1, ahr, ahz, ahn)
      // ---- head logits: quad-first butterfly (12 cross-lane ops vs 24) ----
      float p0 = hw0*h1, p1 = hw1*h1, p2 = hw2*h1, p3 = hw3*h1;
      p0 += __shfl_xor(p0, 1, 64); p1 += __shfl_xor(p1, 1, 64);
      p2 += __shfl_xor(p2, 1, 64); p3 += __shfl_xor(p3, 1, 64);
      p0 += __shfl_xor(p0, 2, 64); p1 += __shfl_xor(p1, 2, 64);
      p2 += __shfl_xor(p2, 2, 64); p3 += __shfl_xor(p3, 2, 64);
      float lq = (vv==0)?p0:(vv==1)?p1:(vv==2)?p2:p3;
      lq += __shfl_xor(lq, 4, 64);
      lq += __shfl_xor(lq, 8, 64);
      lq += __shfl_xor(lq, 16, 64);
      lq += __shfl_xor(lq, 32, 64);
      float lg = lq + hbv;
      // ---- gumbel sample + softmax (quad-parallel, all lanes uniform) ----
      float prt = lg + gmb;
      float mx = lg;
      mx = fmaxf(mx, __shfl_xor(mx, 1, 64));
      mx = fmaxf(mx, __shfl_xor(mx, 2, 64));
      float e = expf(lg - mx);
      float se = e;
      se += __shfl_xor(se, 1, 64);
      se += __shfl_xor(se, 2, 64);
      float prob = e / se;
      // argmax over quad (first-index tie-break)
      float bp = prt; int bv = vv;
      { float o = __shfl_xor(bp, 1, 64); int ov = __shfl_xor(bv, 1, 64);
        if (o > bp || (o == bp && ov < bv)){ bp = o; bv = ov; } }
      { float o = __shfl_xor(bp, 2, 64); int ov = __shfl_xor(bv, 2, 64);
        if (o > bp || (o == bp && ov < bv)){ bp = o; bv = ov; } }
      if (j < 4) out[(size_t)row*SS*VV + (size_t)t*VV + vv] = prob;
      tk = __builtin_amdgcn_readlane(bv, 0);
    }
  }
}

extern "C" void kernel_launch(void* const* d_in, const int* in_sizes, int n_in,
                              void* d_out, int out_size, void* d_ws, size_t ws_size,
                              hipStream_t stream){
  const int*   tokens = (const int*)d_in[0];
  const float* emb    = (const float*)d_in[1];
  const float* eWih0  = (const float*)d_in[2];  const float* eWhh0 = (const float*)d_in[3];
  const float* ebih0  = (const float*)d_in[4];  const float* ebhh0 = (const float*)d_in[5];
  const float* eWih1  = (const float*)d_in[6];  const float* eWhh1 = (const float*)d_in[7];
  const float* ebih1  = (const float*)d_in[8];  const float* ebhh1 = (const float*)d_in[9];
  const float* muW    = (const float*)d_in[10]; const float* mub   = (const float*)d_in[11];
  const float* vaW    = (const float*)d_in[12]; const float* vab   = (const float*)d_in[13];
  const float* demb   = (const float*)d_in[14];
  const float* pW     = (const float*)d_in[15]; const float* pb    = (const float*)d_in[16];
  const float* dWih0  = (const float*)d_in[17]; const float* dWhh0 = (const float*)d_in[18];
  const float* dbih0  = (const float*)d_in[19]; const float* dbhh0 = (const float*)d_in[20];
  const float* dWih1  = (const float*)d_in[21]; const float* dWhh1 = (const float*)d_in[22];
  const float* dbih1  = (const float*)d_in[23]; const float* dbhh1 = (const float*)d_in[24];
  const float* hWp    = (const float*)d_in[25]; const float* hbp   = (const float*)d_in[26];
  float* out = (float*)d_out;
  (void)d_ws; (void)ws_size;

  vae_kernel<<<NB/8, NTHR, 0, stream>>>(tokens, emb,
      eWih0, eWhh0, ebih0, ebhh0, eWih1, eWhh1, ebih1, ebhh1,
      muW, mub, vaW, vab, demb, pW, pb,
      dWih0, dWhh0, dbih0, dbhh0, dWih1, dWhh1, dbih1, dbhh1,
      hWp, hbp, out);
}

// Round 9
// 2554.060 us; speedup vs baseline: 7.5578x; 1.0088x over previous
//
#include <hip/hip_runtime.h>
#include <stdint.h>

typedef unsigned int u32;
typedef unsigned short u16;

#define NB   2048
#define SS   256
#define HH   64
#define VV   4
#define LATD 3
#define NTHR 512   // 8 waves, wave = 1 batch row, 256 blocks = 1 block/CU, 2 waves/SIMD

// float-element offsets in d_out: recons [B,S,1,V], tokens [B,S], mu, log_var
#define TOK_OFF (NB*SS*VV)
#define MU_OFF  (TOK_OFF + NB*SS)
#define LV_OFF  (MU_OFF + NB*LATD)

// ---------- JAX threefry2x32 (20 rounds, explicit) ----------
__device__ __forceinline__ void tf2x32(u32 k0, u32 k1, u32 x0, u32 x1, u32& o0, u32& o1){
  u32 k2 = k0 ^ k1 ^ 0x1BD11BDAu;
  x0 += k0; x1 += k1;
#define TFR(r) { x0 += x1; x1 = (x1<<r)|(x1>>(32-r)); x1 ^= x0; }
  TFR(13) TFR(15) TFR(26) TFR(6)   x0 += k1; x1 += k2 + 1u;
  TFR(17) TFR(29) TFR(16) TFR(24)  x0 += k2; x1 += k0 + 2u;
  TFR(13) TFR(15) TFR(26) TFR(6)   x0 += k0; x1 += k1 + 3u;
  TFR(17) TFR(29) TFR(16) TFR(24)  x0 += k1; x1 += k2 + 4u;
  TFR(13) TFR(15) TFR(26) TFR(6)   x0 += k2; x1 += k0 + 5u;
#undef TFR
  o0 = x0; o1 = x1;
}
// partitionable random_bits (32-bit): bits[i] = x0 ^ x1 of counter (0, i)
__device__ __forceinline__ u32 foldb(u32 k0, u32 k1, u32 i){
  u32 a,b; tf2x32(k0,k1,0u,i,a,b); return a^b;
}
__device__ __forceinline__ float b2u(u32 bits){
  union{u32 i;float f;}c; c.i = (bits>>9) | 0x3f800000u; return c.f - 1.0f;
}
// XLA ErfInv32 (Giles)
__device__ __forceinline__ float erfinv_f(float x){
  float w = -log1pf(-x*x);
  float p;
  if (w < 5.0f){
    w -= 2.5f;
    p = 2.81022636e-08f;
    p = fmaf(p,w, 3.43273939e-07f);
    p = fmaf(p,w,-3.5233877e-06f);
    p = fmaf(p,w,-4.39150654e-06f);
    p = fmaf(p,w, 0.00021858087f);
    p = fmaf(p,w,-0.00125372503f);
    p = fmaf(p,w,-0.00417768164f);
    p = fmaf(p,w, 0.246640727f);
    p = fmaf(p,w, 1.50140941f);
  } else {
    w = sqrtf(w) - 3.0f;
    p = -0.000200214257f;
    p = fmaf(p,w, 0.000100950558f);
    p = fmaf(p,w, 0.00134934322f);
    p = fmaf(p,w,-0.00367342844f);
    p = fmaf(p,w, 0.00573950773f);
    p = fmaf(p,w,-0.0076224613f);
    p = fmaf(p,w, 0.00943887047f);
    p = fmaf(p,w, 1.00167406f);
    p = fmaf(p,w, 2.83297682f);
  }
  return p*x;
}
__device__ __forceinline__ float sigm(float x){ return 1.0f/(1.0f+expf(-x)); }
__device__ __forceinline__ float rl(float x, int l){
  return __int_as_float(__builtin_amdgcn_readlane(__float_as_int(x), l));
}
__device__ __forceinline__ float wred(float x){
  #pragma unroll
  for (int m=1; m<64; m<<=1) x += __shfl_xor(x, m, 64);
  return x;
}

// Single-row GRU mat-vec, REGISTER weights (lane j = output row j per gate).
#define MATVEC1R(Wr, Wz, Wn, xv, ar, az, an)                                   \
  _Pragma("unroll")                                                            \
  for (int k4 = 0; k4 < 16; k4++){                                             \
    float4 wr = Wr[k4];                                                        \
    float4 wz = Wz[k4];                                                        \
    float4 wn = Wn[k4];                                                        \
    float x0 = rl(xv, 4*k4), x1 = rl(xv, 4*k4+1), x2 = rl(xv, 4*k4+2), x3 = rl(xv, 4*k4+3); \
    ar = fmaf(wr.x,x0,ar); ar = fmaf(wr.y,x1,ar); ar = fmaf(wr.z,x2,ar); ar = fmaf(wr.w,x3,ar); \
    az = fmaf(wz.x,x0,az); az = fmaf(wz.y,x1,az); az = fmaf(wz.z,x2,az); az = fmaf(wz.w,x3,az); \
    an = fmaf(wn.x,x0,an); an = fmaf(wn.y,x1,an); an = fmaf(wn.z,x2,an); an = fmaf(wn.w,x3,an); \
  }

// Single-row GRU mat-vec, LDS weights (layout w[k4*192 + gate*64 + j]).
#define MATVEC1L(W, xv, ar, az, an)                                            \
  _Pragma("unroll 2")                                                          \
  for (int k4 = 0; k4 < 16; k4++){                                             \
    float4 wr = W[k4*192 + j];                                                 \
    float4 wz = W[k4*192 + 64 + j];                                            \
    float4 wn = W[k4*192 + 128 + j];                                           \
    float x0 = rl(xv, 4*k4), x1 = rl(xv, 4*k4+1), x2 = rl(xv, 4*k4+2), x3 = rl(xv, 4*k4+3); \
    ar = fmaf(wr.x,x0,ar); ar = fmaf(wr.y,x1,ar); ar = fmaf(wr.z,x2,ar); ar = fmaf(wr.w,x3,ar); \
    az = fmaf(wz.x,x0,az); az = fmaf(wz.y,x1,az); az = fmaf(wz.z,x2,az); az = fmaf(wz.w,x3,az); \
    an = fmaf(wn.x,x0,an); an = fmaf(wn.y,x1,an); an = fmaf(wn.z,x2,an); an = fmaf(wn.w,x3,an); \
  }

#define LOAD_REG_W(G, Ar, Az, An)                                              \
  _Pragma("unroll")                                                            \
  for (int k4 = 0; k4 < 16; k4++){                                             \
    Ar[k4] = G[(j)*16 + k4];                                                   \
    Az[k4] = G[(64 + j)*16 + k4];                                              \
    An[k4] = G[(128 + j)*16 + k4];                                             \
  }

// PIN (enc only): measured best enc config (R9, ~1068 us). Neutral in dec.
#define PIN4(v) asm volatile("" : "+v"(v.x), "+v"(v.y), "+v"(v.z), "+v"(v.w))
#define PIN_W(Ar, Az, An)                                                      \
  _Pragma("unroll")                                                            \
  for (int k4 = 0; k4 < 16; k4++){ PIN4(Ar[k4]); PIN4(Az[k4]); PIN4(An[k4]); }

// =====================================================================
// Encoder: R9 config (measured ~1068 us; ~94% of LDS-pipe floor 983 us).
// Verbatim — do not touch.
// =====================================================================
__global__ __launch_bounds__(NTHR, 2) void enc_kernel(
    const int* __restrict__ tokens, const float* __restrict__ emb,
    const float* __restrict__ Wih0, const float* __restrict__ Whh0,
    const float* __restrict__ bih0, const float* __restrict__ bhh0,
    const float* __restrict__ Wih1, const float* __restrict__ Whh1,
    const float* __restrict__ bih1, const float* __restrict__ bhh1,
    const float* __restrict__ muW, const float* __restrict__ mub,
    const float* __restrict__ vaW, const float* __restrict__ vab,
    const float* __restrict__ pW,  const float* __restrict__ pb,
    float* __restrict__ out, float* __restrict__ hz_ws)
{
  __shared__ float4 wi1[16*192];  // enc_Wih1
  __shared__ float4 wh1[16*192];  // enc_Whh1
  __shared__ float tokT[VV*192];  // input-gate table (incl. bih0) per vocab token

  const int tid = threadIdx.x;
  const int b0  = blockIdx.x * 8;
  const int j   = tid & 63;
  const int wv  = tid >> 6;
  const int row = b0 + wv;

  for (int i4 = tid; i4 < 3072; i4 += NTHR){
    int g = i4 >> 4, k4 = i4 & 15;
    wi1[k4*192 + g] = ((const float4*)Wih1)[i4];
    wh1[k4*192 + g] = ((const float4*)Whh1)[i4];
  }
  if (tid < 192){
    #pragma unroll
    for (int v = 0; v < VV; v++){
      float acc = 0.0f;
      #pragma unroll
      for (int e = 0; e < 8; e++) acc = fmaf(emb[v*8+e], Wih0[tid*8+e], acc);
      tokT[v*192 + tid] = acc + bih0[tid];
    }
  }
  for (int i = tid; i < 8*SS; i += NTHR){
    int rr = i >> 8, tq = i & 255;
    out[TOK_OFF + (b0+rr)*SS + tq] = (float)tokens[(b0+rr)*SS + tq];
  }

  float4 w0r[16], w0z[16], w0n[16];
  {
    const float4* G0 = (const float4*)Whh0;
    LOAD_REG_W(G0, w0r, w0z, w0n)
    PIN_W(w0r, w0z, w0n)
  }
  __syncthreads();

  const float bhr0 = bhh0[j], bhz0 = bhh0[64+j], bhn0 = bhh0[128+j];
  const float bir1 = bih1[j], biz1 = bih1[64+j], bin1 = bih1[128+j];
  const float bhr1 = bhh1[j], bhz1 = bhh1[64+j], bhn1 = bhh1[128+j];

  float h0 = 0.0f, h1 = 0.0f;
  const int tR = row*SS;

  for (int t = 0; t < SS; t++){
    // LICM fence (round-3: hoist -> spill -> 13.3 GB HBM refill traffic)
    asm volatile("" ::: "memory");
    int k = tokens[tR + t];
    float ar=0, az=0, an=0;
    MATVEC1R(w0r, w0z, w0n, h0, ar, az, an)
    {
      float ir = tokT[k*192+j], iz = tokT[k*192+64+j], ig = tokT[k*192+128+j];
      float rg = sigm(ir + ar + bhr0);
      float zg = sigm(iz + az + bhz0);
      float ng = tanhf(ig + rg*(an + bhn0));
      h0 = (1.0f - zg)*ng + zg*h0;
    }
    float air=0, aiz=0, ain=0, ahr=0, ahz=0, ahn=0;
    MATVEC1L(wi1, h0, air, aiz, ain)
    MATVEC1L(wh1, h1, ahr, ahz, ahn)
    {
      float rg = sigm(air + bir1 + ahr + bhr1);
      float zg = sigm(aiz + biz1 + ahz + bhz1);
      float ng = tanhf(ain + bin1 + rg*(ahn + bhn1));
      h1 = (1.0f - zg)*ng + zg*h1;
    }
  }

  const float LO_ = -0.99999994f;   // nextafter(-1, 0) in f32
  {
    float hv = h1;
    int gb = row;
    float mu0,mu1,mu2, lv0,lv1,lv2;
    { float pm = muW[0*64+j]*hv; pm = wred(pm); mu0 = pm + mub[0];
      float pv = vaW[0*64+j]*hv; pv = wred(pv); lv0 = pv + vab[0]; }
    { float pm = muW[1*64+j]*hv; pm = wred(pm); mu1 = pm + mub[1];
      float pv = vaW[1*64+j]*hv; pv = wred(pv); lv1 = pv + vab[1]; }
    { float pm = muW[2*64+j]*hv; pm = wred(pm); mu2 = pm + mub[2];
      float pv = vaW[2*64+j]*hv; pv = wred(pv); lv2 = pv + vab[2]; }
    if (j < 3){
      float mv  = (j==0)?mu0:(j==1)?mu1:mu2;
      float lvv = (j==0)?lv0:(j==1)?lv1:lv2;
      out[MU_OFF + gb*LATD + j] = mv;
      out[LV_OFF + gb*LATD + j] = lvv;
    }
    float z0,z1,z2;
    #pragma unroll
    for (int l = 0; l < 3; l++){
      u32 bits = foldb(0u, 1u, (u32)(gb*LATD + l));
      float u01 = b2u(bits);
      float uu = u01 * 2.0f;      // (hi - lo) rounds to 2.0f
      uu = uu + LO_;
      uu = fmaxf(LO_, uu);
      float ep = 1.41421354f * erfinv_f(uu);
      float lvv = (l==0)?lv0:(l==1)?lv1:lv2;
      float mvv = (l==0)?mu0:(l==1)?mu1:mu2;
      float zv = ep * expf(0.5f*lvv) + mvv;
      if (l==0) z0 = zv; else if (l==1) z1 = zv; else z2 = zv;
    }
    float hzj = pW[j*3+0]*z0;
    hzj += pW[j*3+1]*z1;
    hzj += pW[j*3+2]*z2;
    hzj += pb[j];
    hz_ws[gb*HH + j] = hzj;
  }
}

// =====================================================================
// Decoder: R3 config (measured best overall, 2559.66 total): gumbel table
// precomputed into LDS + layer-0 matvec software-pipelined across the
// backedge. Later additions (wh1 carry R4: neutral; stagger R5: -60us;
// reg-pin R6 / global-stream R7: catastrophic spill; fusion+12-op head
// R8: neutral-negative) are all excluded.
// =====================================================================
__global__ __launch_bounds__(NTHR, 2) void dec_kernel(
    const float* __restrict__ demb,
    const float* __restrict__ Wih0, const float* __restrict__ Whh0,
    const float* __restrict__ bih0, const float* __restrict__ bhh0,
    const float* __restrict__ Wih1, const float* __restrict__ Whh1,
    const float* __restrict__ bih1, const float* __restrict__ bhh1,
    const float* __restrict__ headW, const float* __restrict__ headb,
    const float* __restrict__ hz_ws, float* __restrict__ out)
{
  __shared__ float4 wi1[16*192];  // dec_Wih1
  __shared__ float4 wh1[16*192];  // dec_Whh1
  __shared__ float decT[6*192];   // input-gate table (incl. bih0) per token
  __shared__ u32 sk0[SS], sk1[SS];
  __shared__ float gmbT[8][SS*VV]; // precomputed gumbel per (local row, t, vv)

  const int tid = threadIdx.x;
  const int b0  = blockIdx.x * 8;
  const int j   = tid & 63;
  const int wv  = tid >> 6;
  const int row = b0 + wv;

  for (int i4 = tid; i4 < 3072; i4 += NTHR){
    int g = i4 >> 4, k4 = i4 & 15;
    wi1[k4*192 + g] = ((const float4*)Wih1)[i4];
    wh1[k4*192 + g] = ((const float4*)Whh1)[i4];
  }
  if (tid < 192){
    #pragma unroll
    for (int v = 0; v < 6; v++){
      float acc = 0.0f;
      #pragma unroll 8
      for (int k = 0; k < 64; k++) acc = fmaf(demb[v*64+k], Wih0[tid*64+k], acc);
      decT[v*192 + tid] = acc + bih0[tid];
    }
  }
  // split(key(2), 256): key_t = full output pair of threefry(key2, (0, t))
  if (tid < SS){
    u32 a,b; tf2x32(0u, 2u, 0u, (u32)tid, a, b);
    sk0[tid] = a; sk1[tid] = b;
  }

  float4 w0r[16], w0z[16], w0n[16];
  {
    const float4* G0 = (const float4*)Whh0;
    LOAD_REG_W(G0, w0r, w0z, w0n)   // no PIN: L1 streaming (R7 measured best)
  }
  __syncthreads();

  const float TINY = 1.17549435e-38f;
  // Precompute gumbel table for this wave's row: IDENTICAL formula/inputs as
  // the old in-loop computation -> bit-identical values. Written and read by
  // the same wave only (no extra barrier needed).
  for (int idx = j; idx < SS*VV; idx += 64){
    int t = idx >> 2, v = idx & 3;
    u32 bits = foldb(sk0[t], sk1[t], (u32)(row*VV + v));
    float u01 = b2u(bits);
    float u = u01 + TINY;          // scale (1 - tiny) rounds to 1.0f
    u = fmaxf(TINY, u);
    gmbT[wv][idx] = -logf(-logf(u));
  }

  const float bhr0 = bhh0[j], bhz0 = bhh0[64+j], bhn0 = bhh0[128+j];
  const float bir1 = bih1[j], biz1 = bih1[64+j], bin1 = bih1[128+j];
  const float bhr1 = bhh1[j], bhz1 = bhh1[64+j], bhn1 = bhh1[128+j];
  const float hw0 = headW[0*64+j], hw1 = headW[1*64+j], hw2 = headW[2*64+j], hw3 = headW[3*64+j];
  const float hb0 = headb[0], hb1 = headb[1], hb2 = headb[2], hb3 = headb[3];

  float h0 = hz_ws[row*HH + j];
  float h1 = h0;
  int tk = 4;                     // START token

  const int vv = j & 3;           // lane's vocab slot (quads replicate)

  // pipeline prologue: layer-0 partials for t=0 (from initial h0)
  float ar=0, az=0, an=0;
  MATVEC1R(w0r, w0z, w0n, h0, ar, az, an)

  for (int t = 0; t < SS; t++){
    asm volatile("" ::: "memory");   // LICM fence (see enc_kernel comment)
    // ---- layer 0 gate combine (partials carried from previous iteration;
    //      token from previous step's sample) ----
    {
      float ir = decT[tk*192+j], iz = decT[tk*192+64+j], ig = decT[tk*192+128+j];
      float rg = sigm(ir + ar + bhr0);
      float zg = sigm(iz + az + bhz0);
      float ng = tanhf(ig + rg*(an + bhn0));
      h0 = (1.0f - zg)*ng + zg*h0;
    }
    // ---- layer 1 (both matrices from LDS, separate unroll-2 loops) ----
    float air=0, aiz=0, ain=0, ahr=0, ahz=0, ahn=0;
    MATVEC1L(wi1, h0, air, aiz, ain)
    MATVEC1L(wh1, h1, ahr, ahz, ahn)
    {
      float rg = sigm(air + bir1 + ahr + bhr1);
      float zg = sigm(aiz + biz1 + ahz + bhz1);
      float ng = tanhf(ain + bin1 + rg*(ahn + bhn1));
      h1 = (1.0f - zg)*ng + zg*h1;
    }
    // ---- prefetch gumbel + next-step layer-0 partials (independent of the
    //      head/sample chain below; compiler interleaves to fill its stalls) ----
    float gmb = gmbT[wv][t*VV + vv];
    ar = 0.0f; az = 0.0f; an = 0.0f;
    MATVEC1R(w0r, w0z, w0n, h0, ar, az, an)
    // ---- head logits (wave reductions) ----
    float l0 = wred(hw0*h1) + hb0;
    float l1 = wred(hw1*h1) + hb1;
    float l2 = wred(hw2*h1) + hb2;
    float l3 = wred(hw3*h1) + hb3;
    // ---- gumbel sample + softmax (quad-parallel, all lanes uniform) ----
    float lg = (vv==0)?l0:(vv==1)?l1:(vv==2)?l2:l3;
    float prt = lg + gmb;
    // softmax over quad
    float mx = lg;
    mx = fmaxf(mx, __shfl_xor(mx, 1, 64));
    mx = fmaxf(mx, __shfl_xor(mx, 2, 64));
    float e = expf(lg - mx);
    float se = e;
    se += __shfl_xor(se, 1, 64);
    se += __shfl_xor(se, 2, 64);
    float prob = e / se;
    // argmax over quad (first-index tie-break)
    float bp = prt; int bv = vv;
    { float o = __shfl_xor(bp, 1, 64); int ov = __shfl_xor(bv, 1, 64);
      if (o > bp || (o == bp && ov < bv)){ bp = o; bv = ov; } }
    { float o = __shfl_xor(bp, 2, 64); int ov = __shfl_xor(bv, 2, 64);
      if (o > bp || (o == bp && ov < bv)){ bp = o; bv = ov; } }
    if (j < 4) out[(size_t)row*SS*VV + (size_t)t*VV + vv] = prob;
    tk = __builtin_amdgcn_readlane(bv, 0);
  }
}

extern "C" void kernel_launch(void* const* d_in, const int* in_sizes, int n_in,
                              void* d_out, int out_size, void* d_ws, size_t ws_size,
                              hipStream_t stream){
  const int*   tokens = (const int*)d_in[0];
  const float* emb    = (const float*)d_in[1];
  const float* eWih0  = (const float*)d_in[2];  const float* eWhh0 = (const float*)d_in[3];
  const float* ebih0  = (const float*)d_in[4];  const float* ebhh0 = (const float*)d_in[5];
  const float* eWih1  = (const float*)d_in[6];  const float* eWhh1 = (const float*)d_in[7];
  const float* ebih1  = (const float*)d_in[8];  const float* ebhh1 = (const float*)d_in[9];
  const float* muW    = (const float*)d_in[10]; const float* mub   = (const float*)d_in[11];
  const float* vaW    = (const float*)d_in[12]; const float* vab   = (const float*)d_in[13];
  const float* demb   = (const float*)d_in[14];
  const float* pW     = (const float*)d_in[15]; const float* pb    = (const float*)d_in[16];
  const float* dWih0  = (const float*)d_in[17]; const float* dWhh0 = (const float*)d_in[18];
  const float* dbih0  = (const float*)d_in[19]; const float* dbhh0 = (const float*)d_in[20];
  const float* dWih1  = (const float*)d_in[21]; const float* dWhh1 = (const float*)d_in[22];
  const float* dbih1  = (const float*)d_in[23]; const float* dbhh1 = (const float*)d_in[24];
  const float* hWp    = (const float*)d_in[25]; const float* hbp   = (const float*)d_in[26];
  float* out = (float*)d_out;
  float* hz = (float*)d_ws;   // B*H fp32 = 512 KB scratch

  enc_kernel<<<NB/8, NTHR, 0, stream>>>(tokens, emb,
      eWih0, eWhh0, ebih0, ebhh0, eWih1, eWhh1, ebih1, ebhh1,
      muW, mub, vaW, vab, pW, pb, out, hz);
  dec_kernel<<<NB/8, NTHR, 0, stream>>>(demb,
      dWih0, dWhh0, dbih0, dbhh0, dWih1, dWhh1, dbih1, dbhh1,
      hWp, hbp, hz, out);
}